// Round 1
// baseline (191.150 us; speedup 1.0000x reference)
//
#include <hip/hip_runtime.h>
#include <hip/hip_bf16.h>
#include <cmath>

// Sizes (compile-time)
#define BATCH 8
#define ZDIM 512
#define SDIM 256
#define LVL 16
#define TSZ 16384
#define HID 64
#define NPIX 65536   // 256*256
#define P2H 2654435761u

// per-batch ws layout (floats): W0f[32*64] @0, W1f[64*64] @2048, W2f[64*3] @6144, stride 6400
#define WS_STRIDE 6400

__device__ __forceinline__ float lrelu(float x) {
    return (x >= 0.0f ? x : 0.2f * x) * 1.41421356237309515f;
}

struct ResPack { float rm1[LVL]; };

__global__ __launch_bounds__(256) void k_setup(
    const float* __restrict__ z,
    const float* __restrict__ w1, const float* __restrict__ b1,
    const float* __restrict__ w2, const float* __restrict__ b2,
    const float* __restrict__ w3, const float* __restrict__ b3,
    const float* __restrict__ gen_w,
    const float* __restrict__ a0w, const float* __restrict__ a0b,
    const float* __restrict__ m0w,
    const float* __restrict__ a1w, const float* __restrict__ a1b,
    const float* __restrict__ m1w,
    const float* __restrict__ a2w, const float* __restrict__ a2b,
    const float* __restrict__ m2w,
    float* __restrict__ ws)
{
    const int b = blockIdx.x;
    const int t = threadIdx.x;
    __shared__ float zb[ZDIM];
    __shared__ float sA[SDIM];
    __shared__ float sB[SDIM];
    __shared__ float sc0[32], sc1[64], sc2[64], modv[32];
    __shared__ float d0[64], d1[64], d2[3];

    zb[t]       = z[b * ZDIM + t];
    zb[t + 256] = z[b * ZDIM + 256 + t];
    __syncthreads();

    // style layer 1: [512]->[256]
    float acc = b1[t];
    for (int k = 0; k < ZDIM; ++k) acc = fmaf(zb[k], w1[k * SDIM + t], acc);
    sA[t] = lrelu(acc);
    __syncthreads();
    // layer 2
    acc = b2[t];
    for (int k = 0; k < SDIM; ++k) acc = fmaf(sA[k], w2[k * SDIM + t], acc);
    sB[t] = lrelu(acc);
    __syncthreads();
    // layer 3 -> final style s in sA
    acc = b3[t];
    for (int k = 0; k < SDIM; ++k) acc = fmaf(sB[k], w3[k * SDIM + t], acc);
    sA[t] = lrelu(acc);
    __syncthreads();

    // mod (32), scale0 (32), scale1 (64), scale2 (64) -- disjoint thread groups
    if (t < 32) {
        const int l = t >> 1, f = t & 1;
        float m = 0.0f;
        for (int k = 0; k < SDIM; ++k) m = fmaf(sA[k], gen_w[l * (SDIM * 2) + k * 2 + f], m);
        modv[t] = 1.0f + m;
    } else if (t < 64) {
        const int i = t - 32;
        float sc = a0b[i];
        for (int k = 0; k < SDIM; ++k) sc = fmaf(sA[k], a0w[k * 32 + i], sc);
        sc0[i] = sc;
    } else if (t < 128) {
        const int i = t - 64;
        float sc = a1b[i];
        for (int k = 0; k < SDIM; ++k) sc = fmaf(sA[k], a1w[k * 64 + i], sc);
        sc1[i] = sc;
    } else if (t < 192) {
        const int i = t - 128;
        float sc = a2b[i];
        for (int k = 0; k < SDIM; ++k) sc = fmaf(sA[k], a2w[k * 64 + i], sc);
        sc2[i] = sc;
    }
    __syncthreads();

    // demodulation factors
    if (t < 64) {
        float s2 = 0.0f;
        for (int i = 0; i < 32; ++i) { float v = m0w[i * 64 + t] * sc0[i]; s2 = fmaf(v, v, s2); }
        d0[t] = rsqrtf(s2 + 1e-8f);
    } else if (t < 128) {
        const int j = t - 64;
        float s2 = 0.0f;
        for (int i = 0; i < 64; ++i) { float v = m1w[i * 64 + j] * sc1[i]; s2 = fmaf(v, v, s2); }
        d1[j] = rsqrtf(s2 + 1e-8f);
    } else if (t < 131) {
        const int j = t - 128;
        float s2 = 0.0f;
        for (int i = 0; i < 64; ++i) { float v = m2w[i * 3 + j] * sc2[i]; s2 = fmaf(v, v, s2); }
        d2[j] = rsqrtf(s2 + 1e-8f);
    }
    __syncthreads();

    // effective weights to ws (mod folded into layer-0 input scaling)
    float* wsb = ws + b * WS_STRIDE;
    for (int e = t; e < 2048; e += 256) {
        const int i = e >> 6, j = e & 63;
        wsb[e] = m0w[e] * sc0[i] * d0[j] * modv[i];
    }
    for (int e = t; e < 4096; e += 256) {
        const int i = e >> 6, j = e & 63;
        wsb[2048 + e] = m1w[e] * sc1[i] * d1[j];
    }
    if (t < 192) {
        const int i = t / 3, j = t % 3;
        wsb[6144 + t] = m2w[t] * sc2[i] * d2[j];
    }
}

__global__ __launch_bounds__(256) void k_main(
    const float* __restrict__ base_tables,
    const float* __restrict__ ws,
    const float* __restrict__ m0b,
    const float* __restrict__ m1b,
    const float* __restrict__ m2b,
    float* __restrict__ out,
    ResPack rp)
{
    const int n = blockIdx.x * 256 + threadIdx.x;
    const int b = blockIdx.y;
    const float cx = ((float)(n & 255) + 0.5f) * (1.0f / 256.0f);
    const float cy = ((float)(n >> 8) + 0.5f) * (1.0f / 256.0f);

    // batch-independent raw hash-grid features (mod folded into W0f)
    float rf[32];
#pragma unroll
    for (int l = 0; l < LVL; ++l) {
        const float r1 = rp.rm1[l];
        const float sx = cx * r1, sy = cy * r1;
        const float px = floorf(sx), py = floorf(sy);
        const float fx = sx - px, fy = sy - py;
        const unsigned x0 = (unsigned)px, y0 = (unsigned)py;
        const unsigned x1 = x0 + 1u, y1 = y0 + 1u;
        const unsigned hy0 = y0 * P2H, hy1 = y1 * P2H;
        const float2* tab = reinterpret_cast<const float2*>(base_tables) + (l << 14);
        const float2 f00 = tab[(x0 ^ hy0) & (TSZ - 1)];
        const float2 f01 = tab[(x0 ^ hy1) & (TSZ - 1)];
        const float2 f10 = tab[(x1 ^ hy0) & (TSZ - 1)];
        const float2 f11 = tab[(x1 ^ hy1) & (TSZ - 1)];
        const float w00 = (1.0f - fx) * (1.0f - fy);
        const float w01 = (1.0f - fx) * fy;
        const float w10 = fx * (1.0f - fy);
        const float w11 = fx * fy;
        rf[2 * l]     = w00 * f00.x + w01 * f01.x + w10 * f10.x + w11 * f11.x;
        rf[2 * l + 1] = w00 * f00.y + w01 * f01.y + w10 * f10.y + w11 * f11.y;
    }

    const float* __restrict__ W0 = ws + b * WS_STRIDE;
    const float* __restrict__ W1 = W0 + 2048;
    const float* __restrict__ W2 = W0 + 6144;

    float h0[64];
#pragma unroll
    for (int j = 0; j < 64; ++j) h0[j] = m0b[j];
#pragma unroll
    for (int i = 0; i < 32; ++i) {
        const float a = rf[i];
#pragma unroll
        for (int j = 0; j < 64; ++j) h0[j] = fmaf(a, W0[i * 64 + j], h0[j]);
    }
#pragma unroll
    for (int j = 0; j < 64; ++j) h0[j] = lrelu(h0[j]);

    float h1[64];
#pragma unroll
    for (int j = 0; j < 64; ++j) h1[j] = m1b[j];
#pragma unroll
    for (int i = 0; i < 64; ++i) {
        const float a = h0[i];
#pragma unroll
        for (int j = 0; j < 64; ++j) h1[j] = fmaf(a, W1[i * 64 + j], h1[j]);
    }
#pragma unroll
    for (int j = 0; j < 64; ++j) h1[j] = lrelu(h1[j]);

    float o0 = m2b[0], o1 = m2b[1], o2 = m2b[2];
#pragma unroll
    for (int i = 0; i < 64; ++i) {
        o0 = fmaf(h1[i], W2[i * 3 + 0], o0);
        o1 = fmaf(h1[i], W2[i * 3 + 1], o1);
        o2 = fmaf(h1[i], W2[i * 3 + 2], o2);
    }

    out[(b * 3 + 0) * NPIX + n] = o0;
    out[(b * 3 + 1) * NPIX + n] = o1;
    out[(b * 3 + 2) * NPIX + n] = o2;
}

extern "C" void kernel_launch(void* const* d_in, const int* in_sizes, int n_in,
                              void* d_out, int out_size, void* d_ws, size_t ws_size,
                              hipStream_t stream) {
    const float* z    = (const float*)d_in[0];
    const float* w1   = (const float*)d_in[1];
    const float* b1   = (const float*)d_in[2];
    const float* w2   = (const float*)d_in[3];
    const float* b2   = (const float*)d_in[4];
    const float* w3   = (const float*)d_in[5];
    const float* b3   = (const float*)d_in[6];
    const float* bt   = (const float*)d_in[7];
    const float* genw = (const float*)d_in[8];
    const float* a0w  = (const float*)d_in[9];
    const float* a0b  = (const float*)d_in[10];
    const float* m0w  = (const float*)d_in[11];
    const float* m0b  = (const float*)d_in[12];
    const float* a1w  = (const float*)d_in[13];
    const float* a1b  = (const float*)d_in[14];
    const float* m1w  = (const float*)d_in[15];
    const float* m1b  = (const float*)d_in[16];
    const float* a2w  = (const float*)d_in[17];
    const float* a2b  = (const float*)d_in[18];
    const float* m2w  = (const float*)d_in[19];
    const float* m2b  = (const float*)d_in[20];
    float* ws = (float*)d_ws;
    float* out = (float*)d_out;

    // Replicate numpy's res computation bit-exactly with host libm (float64).
    ResPack rp;
    const double bfac = exp((log(256.0) - log(16.0)) / 15.0);
    for (int l = 0; l < LVL; ++l) {
        const double v = floor(16.0 * pow(bfac, (double)l));
        rp.rm1[l] = (float)v - 1.0f;
    }

    hipLaunchKernelGGL(k_setup, dim3(BATCH), dim3(256), 0, stream,
                       z, w1, b1, w2, b2, w3, b3, genw,
                       a0w, a0b, m0w, a1w, a1b, m1w, a2w, a2b, m2w, ws);

    hipLaunchKernelGGL(k_main, dim3(NPIX / 256, BATCH), dim3(256), 0, stream,
                       bt, ws, m0b, m1b, m2b, out, rp);
}

// Round 2
// 138.807 us; speedup vs baseline: 1.3771x; 1.3771x over previous
//
#include <hip/hip_runtime.h>
#include <hip/hip_bf16.h>
#include <cmath>

// Sizes (compile-time)
#define BATCH 8
#define ZDIM 512
#define SDIM 256
#define LVL 16
#define TSZ 16384
#define HID 64
#define NPIX 65536   // 256*256
#define P2H 2654435761u

// per-batch ws layout (floats): W0f[32*64] @0, W1f[64*64] @2048, W2f[64*4] @6144 (padded), stride 6400
#define WS_STRIDE 6400

__device__ __forceinline__ float lrelu(float x) {
    return (x >= 0.0f ? x : 0.2f * x) * 1.41421356237309515f;
}

struct ResPack { float rm1[LVL]; };

__global__ __launch_bounds__(256) void k_setup(
    const float* __restrict__ z,
    const float* __restrict__ w1, const float* __restrict__ b1,
    const float* __restrict__ w2, const float* __restrict__ b2,
    const float* __restrict__ w3, const float* __restrict__ b3,
    const float* __restrict__ gen_w,
    const float* __restrict__ a0w, const float* __restrict__ a0b,
    const float* __restrict__ m0w,
    const float* __restrict__ a1w, const float* __restrict__ a1b,
    const float* __restrict__ m1w,
    const float* __restrict__ a2w, const float* __restrict__ a2b,
    const float* __restrict__ m2w,
    float* __restrict__ ws)
{
    const int b = blockIdx.x;
    const int t = threadIdx.x;
    __shared__ float zb[ZDIM];
    __shared__ float sA[SDIM];
    __shared__ float sB[SDIM];
    __shared__ float sc0[32], sc1[64], sc2[64], modv[32];
    __shared__ float d0[64], d1[64], d2[3];

    zb[t]       = z[b * ZDIM + t];
    zb[t + 256] = z[b * ZDIM + 256 + t];
    __syncthreads();

    // style layer 1: [512]->[256], 4 accumulators for ILP
    {
        float a0 = 0.f, a1 = 0.f, a2 = 0.f, a3 = 0.f;
#pragma unroll 8
        for (int k = 0; k < ZDIM; k += 4) {
            a0 = fmaf(zb[k + 0], w1[(k + 0) * SDIM + t], a0);
            a1 = fmaf(zb[k + 1], w1[(k + 1) * SDIM + t], a1);
            a2 = fmaf(zb[k + 2], w1[(k + 2) * SDIM + t], a2);
            a3 = fmaf(zb[k + 3], w1[(k + 3) * SDIM + t], a3);
        }
        sA[t] = lrelu(b1[t] + ((a0 + a1) + (a2 + a3)));
    }
    __syncthreads();
    // layer 2
    {
        float a0 = 0.f, a1 = 0.f, a2 = 0.f, a3 = 0.f;
#pragma unroll 8
        for (int k = 0; k < SDIM; k += 4) {
            a0 = fmaf(sA[k + 0], w2[(k + 0) * SDIM + t], a0);
            a1 = fmaf(sA[k + 1], w2[(k + 1) * SDIM + t], a1);
            a2 = fmaf(sA[k + 2], w2[(k + 2) * SDIM + t], a2);
            a3 = fmaf(sA[k + 3], w2[(k + 3) * SDIM + t], a3);
        }
        sB[t] = lrelu(b2[t] + ((a0 + a1) + (a2 + a3)));
    }
    __syncthreads();
    // layer 3 -> final style s in sA
    {
        float a0 = 0.f, a1 = 0.f, a2 = 0.f, a3 = 0.f;
#pragma unroll 8
        for (int k = 0; k < SDIM; k += 4) {
            a0 = fmaf(sB[k + 0], w3[(k + 0) * SDIM + t], a0);
            a1 = fmaf(sB[k + 1], w3[(k + 1) * SDIM + t], a1);
            a2 = fmaf(sB[k + 2], w3[(k + 2) * SDIM + t], a2);
            a3 = fmaf(sB[k + 3], w3[(k + 3) * SDIM + t], a3);
        }
        sA[t] = lrelu(b3[t] + ((a0 + a1) + (a2 + a3)));
    }
    __syncthreads();

    // mod (32), scale0 (32), scale1 (64), scale2 (64) -- disjoint thread groups
    if (t < 32) {
        const int l = t >> 1, f = t & 1;
        float m = 0.0f;
        for (int k = 0; k < SDIM; ++k) m = fmaf(sA[k], gen_w[l * (SDIM * 2) + k * 2 + f], m);
        modv[t] = 1.0f + m;
    } else if (t < 64) {
        const int i = t - 32;
        float sc = a0b[i];
        for (int k = 0; k < SDIM; ++k) sc = fmaf(sA[k], a0w[k * 32 + i], sc);
        sc0[i] = sc;
    } else if (t < 128) {
        const int i = t - 64;
        float sc = a1b[i];
        for (int k = 0; k < SDIM; ++k) sc = fmaf(sA[k], a1w[k * 64 + i], sc);
        sc1[i] = sc;
    } else if (t < 192) {
        const int i = t - 128;
        float sc = a2b[i];
        for (int k = 0; k < SDIM; ++k) sc = fmaf(sA[k], a2w[k * 64 + i], sc);
        sc2[i] = sc;
    }
    __syncthreads();

    // demodulation factors
    if (t < 64) {
        float s2 = 0.0f;
        for (int i = 0; i < 32; ++i) { float v = m0w[i * 64 + t] * sc0[i]; s2 = fmaf(v, v, s2); }
        d0[t] = rsqrtf(s2 + 1e-8f);
    } else if (t < 128) {
        const int j = t - 64;
        float s2 = 0.0f;
        for (int i = 0; i < 64; ++i) { float v = m1w[i * 64 + j] * sc1[i]; s2 = fmaf(v, v, s2); }
        d1[j] = rsqrtf(s2 + 1e-8f);
    } else if (t < 131) {
        const int j = t - 128;
        float s2 = 0.0f;
        for (int i = 0; i < 64; ++i) { float v = m2w[i * 3 + j] * sc2[i]; s2 = fmaf(v, v, s2); }
        d2[j] = rsqrtf(s2 + 1e-8f);
    }
    __syncthreads();

    // effective weights to ws (mod folded into layer-0 input scaling)
    float* wsb = ws + b * WS_STRIDE;
    for (int e = t; e < 2048; e += 256) {
        const int i = e >> 6, j = e & 63;
        wsb[e] = m0w[e] * sc0[i] * d0[j] * modv[i];
    }
    for (int e = t; e < 4096; e += 256) {
        const int i = e >> 6, j = e & 63;
        wsb[2048 + e] = m1w[e] * sc1[i] * d1[j];
    }
    {   // W2 padded to [64][4], col 3 = 0
        const int i = t >> 2, j = t & 3;
        wsb[6144 + t] = (j < 3) ? m2w[i * 3 + j] * sc2[i] * d2[j] : 0.0f;
    }
}

__global__ __launch_bounds__(256) void k_main(
    const float* __restrict__ base_tables,
    const float* __restrict__ ws,
    const float* __restrict__ m0b,
    const float* __restrict__ m1b,
    const float* __restrict__ m2b,
    float* __restrict__ out,
    ResPack rp)
{
    __shared__ float wl[WS_STRIDE + 64 + 64 + 4];  // weights + biases
    const int t = threadIdx.x;
    const int n = blockIdx.x * 256 + t;
    const int b = blockIdx.y;

    // stage this batch's effective weights into LDS (coalesced float4)
    {
        const float4* src = reinterpret_cast<const float4*>(ws + b * WS_STRIDE);
        float4* dst = reinterpret_cast<float4*>(wl);
        for (int e = t; e < WS_STRIDE / 4; e += 256) dst[e] = src[e];
        if (t < 64)        wl[WS_STRIDE + t] = m0b[t];
        else if (t < 128)  wl[WS_STRIDE + t] = m1b[t - 64];
        else if (t < 131)  wl[WS_STRIDE + 64 + t - 64] = m2b[t - 128];
    }
    __syncthreads();

    const float cx = ((float)(n & 255) + 0.5f) * (1.0f / 256.0f);
    const float cy = ((float)(n >> 8) + 0.5f) * (1.0f / 256.0f);

    // batch-independent raw hash-grid features (mod folded into W0f)
    float rf[32];
#pragma unroll
    for (int l = 0; l < LVL; ++l) {
        const float r1 = rp.rm1[l];
        const float sx = cx * r1, sy = cy * r1;
        const float px = floorf(sx), py = floorf(sy);
        const float fx = sx - px, fy = sy - py;
        const unsigned x0 = (unsigned)px, y0 = (unsigned)py;
        const unsigned x1 = x0 + 1u, y1 = y0 + 1u;
        const unsigned hy0 = y0 * P2H, hy1 = y1 * P2H;
        const float2* tab = reinterpret_cast<const float2*>(base_tables) + (l << 14);
        const float2 f00 = tab[(x0 ^ hy0) & (TSZ - 1)];
        const float2 f01 = tab[(x0 ^ hy1) & (TSZ - 1)];
        const float2 f10 = tab[(x1 ^ hy0) & (TSZ - 1)];
        const float2 f11 = tab[(x1 ^ hy1) & (TSZ - 1)];
        const float w00 = (1.0f - fx) * (1.0f - fy);
        const float w01 = (1.0f - fx) * fy;
        const float w10 = fx * (1.0f - fy);
        const float w11 = fx * fy;
        rf[2 * l]     = w00 * f00.x + w01 * f01.x + w10 * f10.x + w11 * f11.x;
        rf[2 * l + 1] = w00 * f00.y + w01 * f01.y + w10 * f10.y + w11 * f11.y;
    }

    const float4* __restrict__ W0v = reinterpret_cast<const float4*>(wl);          // [32][16]
    const float4* __restrict__ W1v = reinterpret_cast<const float4*>(wl + 2048);   // [64][16]
    const float4* __restrict__ W2v = reinterpret_cast<const float4*>(wl + 6144);   // [64][1]
    const float* __restrict__ B0 = wl + WS_STRIDE;
    const float* __restrict__ B1 = wl + WS_STRIDE + 64;
    const float* __restrict__ B2 = wl + WS_STRIDE + 128;

    float h0[64];
#pragma unroll
    for (int j = 0; j < 64; ++j) h0[j] = B0[j];
#pragma unroll
    for (int i = 0; i < 32; ++i) {
        const float a = rf[i];
#pragma unroll
        for (int q = 0; q < 16; ++q) {
            const float4 w = W0v[i * 16 + q];
            h0[4 * q + 0] = fmaf(a, w.x, h0[4 * q + 0]);
            h0[4 * q + 1] = fmaf(a, w.y, h0[4 * q + 1]);
            h0[4 * q + 2] = fmaf(a, w.z, h0[4 * q + 2]);
            h0[4 * q + 3] = fmaf(a, w.w, h0[4 * q + 3]);
        }
    }
#pragma unroll
    for (int j = 0; j < 64; ++j) h0[j] = lrelu(h0[j]);

    float h1[64];
#pragma unroll
    for (int j = 0; j < 64; ++j) h1[j] = B1[j];
#pragma unroll
    for (int i = 0; i < 64; ++i) {
        const float a = h0[i];
#pragma unroll
        for (int q = 0; q < 16; ++q) {
            const float4 w = W1v[i * 16 + q];
            h1[4 * q + 0] = fmaf(a, w.x, h1[4 * q + 0]);
            h1[4 * q + 1] = fmaf(a, w.y, h1[4 * q + 1]);
            h1[4 * q + 2] = fmaf(a, w.z, h1[4 * q + 2]);
            h1[4 * q + 3] = fmaf(a, w.w, h1[4 * q + 3]);
        }
    }
#pragma unroll
    for (int j = 0; j < 64; ++j) h1[j] = lrelu(h1[j]);

    float o0 = B2[0], o1 = B2[1], o2 = B2[2];
#pragma unroll
    for (int i = 0; i < 64; ++i) {
        const float4 w = W2v[i];
        o0 = fmaf(h1[i], w.x, o0);
        o1 = fmaf(h1[i], w.y, o1);
        o2 = fmaf(h1[i], w.z, o2);
    }

    out[(b * 3 + 0) * NPIX + n] = o0;
    out[(b * 3 + 1) * NPIX + n] = o1;
    out[(b * 3 + 2) * NPIX + n] = o2;
}

extern "C" void kernel_launch(void* const* d_in, const int* in_sizes, int n_in,
                              void* d_out, int out_size, void* d_ws, size_t ws_size,
                              hipStream_t stream) {
    const float* z    = (const float*)d_in[0];
    const float* w1   = (const float*)d_in[1];
    const float* b1   = (const float*)d_in[2];
    const float* w2   = (const float*)d_in[3];
    const float* b2   = (const float*)d_in[4];
    const float* w3   = (const float*)d_in[5];
    const float* b3   = (const float*)d_in[6];
    const float* bt   = (const float*)d_in[7];
    const float* genw = (const float*)d_in[8];
    const float* a0w  = (const float*)d_in[9];
    const float* a0b  = (const float*)d_in[10];
    const float* m0w  = (const float*)d_in[11];
    const float* m0b  = (const float*)d_in[12];
    const float* a1w  = (const float*)d_in[13];
    const float* a1b  = (const float*)d_in[14];
    const float* m1w  = (const float*)d_in[15];
    const float* m1b  = (const float*)d_in[16];
    const float* a2w  = (const float*)d_in[17];
    const float* a2b  = (const float*)d_in[18];
    const float* m2w  = (const float*)d_in[19];
    const float* m2b  = (const float*)d_in[20];
    float* ws = (float*)d_ws;
    float* out = (float*)d_out;

    // Replicate numpy's res computation bit-exactly with host libm (float64).
    ResPack rp;
    const double bfac = exp((log(256.0) - log(16.0)) / 15.0);
    for (int l = 0; l < LVL; ++l) {
        const double v = floor(16.0 * pow(bfac, (double)l));
        rp.rm1[l] = (float)v - 1.0f;
    }

    hipLaunchKernelGGL(k_setup, dim3(BATCH), dim3(256), 0, stream,
                       z, w1, b1, w2, b2, w3, b3, genw,
                       a0w, a0b, m0w, a1w, a1b, m1w, a2w, a2b, m2w, ws);

    hipLaunchKernelGGL(k_main, dim3(NPIX / 256, BATCH), dim3(256), 0, stream,
                       bt, ws, m0b, m1b, m2b, out, rp);
}